// Round 4
// baseline (173.818 us; speedup 1.0000x reference)
//
#include <hip/hip_runtime.h>
#include <hip/hip_fp16.h>
#include <math.h>

#define NEG_SLOPE 0.2f

typedef _Float16 f16x2 __attribute__((ext_vector_type(2)));
typedef _Float16 f16x8 __attribute__((ext_vector_type(8)));
typedef float f32x4 __attribute__((ext_vector_type(4)));

__device__ __forceinline__ float fdot2f(unsigned int a, unsigned int b, float c) {
#if __has_builtin(__builtin_amdgcn_fdot2)
    return __builtin_amdgcn_fdot2(__builtin_bit_cast(f16x2, a),
                                  __builtin_bit_cast(f16x2, b), c, false);
#else
    __half2 ah = __builtin_bit_cast(__half2, a), bh = __builtin_bit_cast(__half2, b);
    float2 af = __half22float2(ah), bf = __half22float2(bh);
    return c + af.x * bf.x + af.y * bf.y;
#endif
}

// ---------------------------------------------------------------------------
// Kernel 0: segment offsets from sorted dst.
// ---------------------------------------------------------------------------
__global__ __launch_bounds__(256) void seg_offsets_kernel(
    const int* __restrict__ dst, int* __restrict__ off, int E, int N)
{
    int i = blockIdx.x * blockDim.x + threadIdx.x;
    if (i >= E) return;
    int d = dst[i];
    int prev = (i == 0) ? -1 : dst[i - 1];
    for (int n = prev + 1; n <= d; ++n) off[n] = i;
    if (i == E - 1) {
        for (int n = d + 1; n <= N; ++n) off[n] = E;
    }
}

// ---------------------------------------------------------------------------
// Kernel 1: prep — W fp32 [k][c] -> fp16 transposed [c][k]; attn vecs -> fp16.
// ---------------------------------------------------------------------------
__global__ __launch_bounds__(256) void prep_kernel(
    const float* __restrict__ W, const float* __restrict__ attn_l,
    const float* __restrict__ attn_r, __half* __restrict__ w16t,
    __half* __restrict__ al16, __half* __restrict__ ar16)
{
    int tid = blockIdx.x * 256 + threadIdx.x;     // 16384 threads
    int c = tid >> 7, k = tid & 127;
    w16t[c * 128 + k] = __float2half(W[k * 128 + c]);
    if (tid < 128) {
        al16[tid] = __float2half(attn_l[tid]);
        ar16[tid] = __float2half(attn_r[tid]);
    }
}

// ---------------------------------------------------------------------------
// Kernel 2: proj — feat16 = fp16(h) @ fp16(W) via MFMA 16x16x32_f16.
// Block 256 thr = 4 waves; tile 64 nodes x 128 cols; K-loop 4 x 32.
// LDS: hl [64][128] f16 (16KB) + wl [128][128] f16 (32KB), XOR-swizzled.
// ---------------------------------------------------------------------------
__global__ __launch_bounds__(256) void proj_kernel(
    const float* __restrict__ h, const __half* __restrict__ w16t,
    __half* __restrict__ feat, int N)
{
    __shared__ __half hl[64 * 128];
    __shared__ __half wl[128 * 128];
    const int t = threadIdx.x;
    const int nodeBase = blockIdx.x * 64;

    // stage W16t -> wl (swizzled rows: byte ^ ((row&7)<<4)).
    // Each col = 128 halves = 256 B = SIXTEEN 16B chunks (r3 bug: used 8 -> OOB).
#pragma unroll
    for (int i = 0; i < 8; ++i) {
        int ch = t + i * 256;                     // 2048 16B chunks
        int col = ch >> 4, k8 = ch & 15;          // col 0..127, chunk-in-col 0..15
        uint4 v = *(const uint4*)(w16t + col * 128 + k8 * 8);
        int byte = col * 256 + k8 * 16;
        *(uint4*)((char*)wl + (byte ^ ((col & 7) << 4))) = v;
    }
    // stage h (fp32 -> fp16) -> hl swizzled
#pragma unroll
    for (int i = 0; i < 8; ++i) {
        int slot = t + i * 256;                   // 2048 float4 slots
        int row = slot >> 5, c4 = slot & 31;
        int gn = nodeBase + row;
        float4 v = make_float4(0.f, 0.f, 0.f, 0.f);
        if (gn < N) v = *(const float4*)(h + (size_t)gn * 128 + c4 * 4);
        __half2 p0 = __floats2half2_rn(v.x, v.y);
        __half2 p1 = __floats2half2_rn(v.z, v.w);
        uint2 u = make_uint2(__builtin_bit_cast(unsigned int, p0),
                             __builtin_bit_cast(unsigned int, p1));
        int byte = row * 256 + c4 * 8;
        *(uint2*)((char*)hl + (byte ^ ((row & 7) << 4))) = u;
    }
    __syncthreads();

    const int l = t & 63, wave = t >> 6;
    const int arow = wave * 16 + (l & 15);        // A row = node within block
    const int kg = l >> 4;                        // k-group (8 contiguous k)
    f32x4 acc[8];
#pragma unroll
    for (int i = 0; i < 8; ++i) acc[i] = (f32x4){0.f, 0.f, 0.f, 0.f};

#pragma unroll
    for (int kt = 0; kt < 4; ++kt) {
        const int kb = (kt * 32 + kg * 8) * 2;    // byte offset of the 8 halves
        f16x8 a = *(const f16x8*)((const char*)hl +
                    ((arow * 256 + kb) ^ ((arow & 7) << 4)));
#pragma unroll
        for (int ct = 0; ct < 8; ++ct) {
            int bcol = ct * 16 + (l & 15);        // B col
            f16x8 b = *(const f16x8*)((const char*)wl +
                        ((bcol * 256 + kb) ^ ((bcol & 7) << 4)));
            acc[ct] = __builtin_amdgcn_mfma_f32_16x16x32_f16(a, b, acc[ct], 0, 0, 0);
        }
    }

    // epilogue: D[row=(l>>4)*4+r][col=ct*16+(l&15)]
    const int nodeLo = nodeBase + wave * 16 + (l >> 4) * 4;
    const int colLo = l & 15;
#pragma unroll
    for (int ct = 0; ct < 8; ++ct) {
#pragma unroll
        for (int r = 0; r < 4; ++r) {
            int node = nodeLo + r;
            if (node < N)
                feat[(size_t)node * 128 + ct * 16 + colLo] = __float2half(acc[ct][r]);
        }
    }
}

// ---------------------------------------------------------------------------
// Kernel 3: el/er from feat16 (thread per (node, head); coalesced).
// ---------------------------------------------------------------------------
__global__ __launch_bounds__(256) void eler_kernel(
    const __half* __restrict__ feat, const __half* __restrict__ al16,
    const __half* __restrict__ ar16, float* __restrict__ el,
    float* __restrict__ er, int N)
{
    int tid = blockIdx.x * 256 + threadIdx.x;
    if (tid >= N * 4) return;
    int n = tid >> 2, hh = tid & 3;
    const uint4* f4 = (const uint4*)(feat + (size_t)n * 128 + hh * 32);
    const uint4* a4 = (const uint4*)(al16 + hh * 32);
    const uint4* b4 = (const uint4*)(ar16 + hh * 32);
    float lv = 0.f, rv = 0.f;
#pragma unroll
    for (int j = 0; j < 4; ++j) {
        uint4 fv = f4[j], av = a4[j], bv = b4[j];
        lv = fdot2f(fv.x, av.x, lv); rv = fdot2f(fv.x, bv.x, rv);
        lv = fdot2f(fv.y, av.y, lv); rv = fdot2f(fv.y, bv.y, rv);
        lv = fdot2f(fv.z, av.z, lv); rv = fdot2f(fv.z, bv.z, rv);
        lv = fdot2f(fv.w, av.w, lv); rv = fdot2f(fv.w, bv.w, rv);
    }
    el[tid] = lv;
    er[tid] = rv;
}

// ---------------------------------------------------------------------------
// Kernel 4: edge weights w_t[h][e] = fp16(exp(leaky(el[src]+er[dst]))).
// ---------------------------------------------------------------------------
__global__ __launch_bounds__(256) void edgew_kernel(
    const float* __restrict__ el, const float* __restrict__ er,
    const int* __restrict__ src, const int* __restrict__ dst,
    __half* __restrict__ w_t, int E)
{
    int e = blockIdx.x * 256 + threadIdx.x;
    int hh = blockIdx.y;
    if (e >= E) return;
    int sv = src[e], dv = dst[e];
    float sc = el[sv * 4 + hh] + er[dv * 4 + hh];
    sc = sc > 0.f ? sc : NEG_SLOPE * sc;
    w_t[(size_t)hh * E + e] = __float2half(__expf(sc));
}

// ---------------------------------------------------------------------------
// Kernel 5: aggregate. One wave per node; lane l owns features 2l,2l+1.
// Per edge-pair: uniform src loads (readfirstlane->scalar base), half2 w
// stream load, v_perm regroup, 3x v_dot2_f32_f16.
// ---------------------------------------------------------------------------
__global__ __launch_bounds__(256) void aggregate_kernel(
    const __half* __restrict__ feat, const __half* __restrict__ w_t,
    const int* __restrict__ off, const int* __restrict__ src,
    const float* __restrict__ bias, float* __restrict__ out, int N, int E)
{
    const int wid = (int)((blockIdx.x * blockDim.x + threadIdx.x) >> 6);
    const int l = threadIdx.x & 63;
    if (wid >= N) return;
    const int n = wid;
    int s = off[n];
    const int e = off[n + 1];
    const int f0 = 2 * l;
    const float b0 = bias[f0], b1 = bias[f0 + 1];
    float* outp = out + (size_t)n * 128;
    if (s >= e) {
        outp[f0] = fmaxf(b0, 0.f);
        outp[f0 + 1] = fmaxf(b1, 0.f);
        return;
    }

    const __half* wp = w_t + (size_t)(l >> 4) * E;  // per-head stream
    float ax = 0.f, ay = 0.f, dn = 0.f;
    const unsigned int one2 = 0x3C003C00u;          // {1.0h, 1.0h}

    if (s & 1) {                                    // align w-pairs to dword
        int sv = __builtin_amdgcn_readfirstlane(src[s]);
        float w = __half2float(wp[s]);
        __half2 gh = *(const __half2*)(feat + (size_t)sv * 128 + f0);
        float2 fv = __half22float2(gh);
        ax += w * fv.x; ay += w * fv.y; dn += w;
        ++s;
    }
    int ei = s;
    for (; ei + 2 <= e; ei += 2) {
        int sv0 = __builtin_amdgcn_readfirstlane(src[ei]);
        int sv1 = __builtin_amdgcn_readfirstlane(src[ei + 1]);
        unsigned int w2 = *(const unsigned int*)(wp + ei);
        unsigned int g0 = *(const unsigned int*)(feat + (size_t)sv0 * 128 + f0);
        unsigned int g1 = *(const unsigned int*)(feat + (size_t)sv1 * 128 + f0);
        unsigned int lo = __builtin_amdgcn_perm(g1, g0, 0x05040100u); // {x0,x1}
        unsigned int hi = __builtin_amdgcn_perm(g1, g0, 0x07060302u); // {y0,y1}
        ax = fdot2f(w2, lo, ax);
        ay = fdot2f(w2, hi, ay);
        dn = fdot2f(w2, one2, dn);
    }
    if (ei < e) {                                   // tail edge
        int sv = __builtin_amdgcn_readfirstlane(src[ei]);
        float w = __half2float(wp[ei]);
        __half2 gh = *(const __half2*)(feat + (size_t)sv * 128 + f0);
        float2 fv = __half22float2(gh);
        ax += w * fv.x; ay += w * fv.y; dn += w;
    }
    const float inv = 1.f / dn;
    outp[f0] = fmaxf(ax * inv + b0, 0.f);
    outp[f0 + 1] = fmaxf(ay * inv + b1, 0.f);
}

// ---------------------------------------------------------------------------
extern "C" void kernel_launch(void* const* d_in, const int* in_sizes, int n_in,
                              void* d_out, int out_size, void* d_ws, size_t ws_size,
                              hipStream_t stream)
{
    const float* h      = (const float*)d_in[0];
    const int*   src    = (const int*)d_in[1];
    const int*   dst    = (const int*)d_in[2];
    const float* W      = (const float*)d_in[3];
    const float* attn_l = (const float*)d_in[4];
    const float* attn_r = (const float*)d_in[5];
    const float* bias   = (const float*)d_in[6];
    const int N = in_sizes[0] / 128;
    const int E = in_sizes[1];
    float* out = (float*)d_out;

    // workspace (all offsets multiples of 16B)
    char* ws = (char*)d_ws;
    __half* feat = (__half*)ws;            ws += (size_t)N * 128 * sizeof(__half); // 25.6MB
    float*  el   = (float*)ws;             ws += (size_t)N * 4 * sizeof(float);    // 1.6MB
    float*  er   = (float*)ws;             ws += (size_t)N * 4 * sizeof(float);    // 1.6MB
    __half* w_t  = (__half*)ws;            ws += (size_t)E * 4 * sizeof(__half);   // 12.8MB
    __half* w16t = (__half*)ws;            ws += 128 * 128 * sizeof(__half);       // 32KB
    __half* al16 = (__half*)ws;            ws += 256;
    __half* ar16 = (__half*)ws;            ws += 256;
    int*    off  = (int*)ws;

    hipLaunchKernelGGL(seg_offsets_kernel, dim3((E + 255) / 256), dim3(256), 0, stream,
                       dst, off, E, N);
    hipLaunchKernelGGL(prep_kernel, dim3(64), dim3(256), 0, stream,
                       W, attn_l, attn_r, w16t, al16, ar16);
    hipLaunchKernelGGL(proj_kernel, dim3((N + 63) / 64), dim3(256), 0, stream,
                       h, w16t, feat, N);
    hipLaunchKernelGGL(eler_kernel, dim3((N * 4 + 255) / 256), dim3(256), 0, stream,
                       feat, al16, ar16, el, er, N);
    hipLaunchKernelGGL(edgew_kernel, dim3((E + 255) / 256, 4), dim3(256), 0, stream,
                       el, er, src, dst, w_t, E);
    hipLaunchKernelGGL(aggregate_kernel, dim3((N + 3) / 4), dim3(256), 0, stream,
                       feat, w_t, off, src, bias, out, N, E);
}

// Round 5
// 136.380 us; speedup vs baseline: 1.2745x; 1.2745x over previous
//
#include <hip/hip_runtime.h>
#include <hip/hip_fp16.h>
#include <math.h>

#define NEG_SLOPE 0.2f

typedef _Float16 f16x2 __attribute__((ext_vector_type(2)));
typedef _Float16 f16x8 __attribute__((ext_vector_type(8)));
typedef float f32x4 __attribute__((ext_vector_type(4)));

__device__ __forceinline__ float fdot2f(unsigned int a, unsigned int b, float c) {
#if __has_builtin(__builtin_amdgcn_fdot2)
    return __builtin_amdgcn_fdot2(__builtin_bit_cast(f16x2, a),
                                  __builtin_bit_cast(f16x2, b), c, false);
#else
    __half2 ah = __builtin_bit_cast(__half2, a), bh = __builtin_bit_cast(__half2, b);
    float2 af = __half22float2(ah), bf = __half22float2(bh);
    return c + af.x * bf.x + af.y * bf.y;
#endif
}

// ---------------------------------------------------------------------------
// Kernel 0: segment offsets from sorted dst.
// ---------------------------------------------------------------------------
__global__ __launch_bounds__(256) void seg_offsets_kernel(
    const int* __restrict__ dst, int* __restrict__ off, int E, int N)
{
    int i = blockIdx.x * blockDim.x + threadIdx.x;
    if (i >= E) return;
    int d = dst[i];
    int prev = (i == 0) ? -1 : dst[i - 1];
    for (int n = prev + 1; n <= d; ++n) off[n] = i;
    if (i == E - 1) {
        for (int n = d + 1; n <= N; ++n) off[n] = E;
    }
}

// ---------------------------------------------------------------------------
// Kernel 1: prep — W fp32 [k][c] -> fp16 transposed [c][k].
// ---------------------------------------------------------------------------
__global__ __launch_bounds__(256) void prep_kernel(
    const float* __restrict__ W, __half* __restrict__ w16t)
{
    int tid = blockIdx.x * 256 + threadIdx.x;     // 16384 threads
    int c = tid >> 7, k = tid & 127;
    w16t[c * 128 + k] = __float2half(W[k * 128 + c]);
}

// ---------------------------------------------------------------------------
// Kernel 2: proj — feat16 = fp16(h) @ fp16(W) via MFMA 16x16x32_f16,
// with FUSED el/er epilogue (head of col ct*16+c is ct>>1).
// Block 256 thr = 4 waves; tile 64 nodes x 128 cols; K-loop 4 x 32.
// ---------------------------------------------------------------------------
__global__ __launch_bounds__(256) void proj_kernel(
    const float* __restrict__ h, const __half* __restrict__ w16t,
    const float* __restrict__ attn_l, const float* __restrict__ attn_r,
    __half* __restrict__ feat, float* __restrict__ el, float* __restrict__ er,
    int N)
{
    __shared__ __half hl[64 * 128];
    __shared__ __half wl[128 * 128];
    const int t = threadIdx.x;
    const int nodeBase = blockIdx.x * 64;

    // stage W16t -> wl (swizzled rows: byte ^ ((row&7)<<4)); 16 chunks/col.
#pragma unroll
    for (int i = 0; i < 8; ++i) {
        int ch = t + i * 256;                     // 2048 16B chunks
        int col = ch >> 4, k8 = ch & 15;
        uint4 v = *(const uint4*)(w16t + col * 128 + k8 * 8);
        int byte = col * 256 + k8 * 16;
        *(uint4*)((char*)wl + (byte ^ ((col & 7) << 4))) = v;
    }
    // stage h (fp32 -> fp16) -> hl swizzled
#pragma unroll
    for (int i = 0; i < 8; ++i) {
        int slot = t + i * 256;                   // 2048 float4 slots
        int row = slot >> 5, c4 = slot & 31;
        int gn = nodeBase + row;
        float4 v = make_float4(0.f, 0.f, 0.f, 0.f);
        if (gn < N) v = *(const float4*)(h + (size_t)gn * 128 + c4 * 4);
        __half2 p0 = __floats2half2_rn(v.x, v.y);
        __half2 p1 = __floats2half2_rn(v.z, v.w);
        uint2 u = make_uint2(__builtin_bit_cast(unsigned int, p0),
                             __builtin_bit_cast(unsigned int, p1));
        int byte = row * 256 + c4 * 8;
        *(uint2*)((char*)hl + (byte ^ ((row & 7) << 4))) = u;
    }
    __syncthreads();

    const int l = t & 63, wave = t >> 6;
    const int arow = wave * 16 + (l & 15);
    const int kg = l >> 4;
    f32x4 acc[8];
#pragma unroll
    for (int i = 0; i < 8; ++i) acc[i] = (f32x4){0.f, 0.f, 0.f, 0.f};

#pragma unroll
    for (int kt = 0; kt < 4; ++kt) {
        const int kb = (kt * 32 + kg * 8) * 2;
        f16x8 a = *(const f16x8*)((const char*)hl +
                    ((arow * 256 + kb) ^ ((arow & 7) << 4)));
#pragma unroll
        for (int ct = 0; ct < 8; ++ct) {
            int bcol = ct * 16 + (l & 15);
            f16x8 b = *(const f16x8*)((const char*)wl +
                        ((bcol * 256 + kb) ^ ((bcol & 7) << 4)));
            acc[ct] = __builtin_amdgcn_mfma_f32_16x16x32_f16(a, b, acc[ct], 0, 0, 0);
        }
    }

    // ---- feat store: D[row=(l>>4)*4+r][col=ct*16+(l&15)]
    const int nodeLo = nodeBase + wave * 16 + (l >> 4) * 4;
    const int colLo = l & 15;
#pragma unroll
    for (int ct = 0; ct < 8; ++ct) {
#pragma unroll
        for (int r = 0; r < 4; ++r) {
            int node = nodeLo + r;
            if (node < N)
                feat[(size_t)node * 128 + ct * 16 + colLo] = __float2half(acc[ct][r]);
        }
    }

    // ---- fused el/er: head(col) = ct>>1; per-lane partials then 16-lane reduce
    float pl[4][4], pr[4][4];                     // [head][row]
#pragma unroll
    for (int hh = 0; hh < 4; ++hh) {
        float al0 = attn_l[hh * 32 + colLo];
        float al1 = attn_l[hh * 32 + 16 + colLo];
        float ar0 = attn_r[hh * 32 + colLo];
        float ar1 = attn_r[hh * 32 + 16 + colLo];
#pragma unroll
        for (int r = 0; r < 4; ++r) {
            pl[hh][r] = acc[2 * hh][r] * al0 + acc[2 * hh + 1][r] * al1;
            pr[hh][r] = acc[2 * hh][r] * ar0 + acc[2 * hh + 1][r] * ar1;
        }
    }
#pragma unroll
    for (int msk = 1; msk <= 8; msk <<= 1) {
#pragma unroll
        for (int hh = 0; hh < 4; ++hh)
#pragma unroll
            for (int r = 0; r < 4; ++r) {
                pl[hh][r] += __shfl_xor(pl[hh][r], msk);
                pr[hh][r] += __shfl_xor(pr[hh][r], msk);
            }
    }
    if (colLo == 0) {
#pragma unroll
        for (int r = 0; r < 4; ++r) {
            int node = nodeLo + r;
            if (node < N) {
                *(float4*)(el + (size_t)node * 4) =
                    make_float4(pl[0][r], pl[1][r], pl[2][r], pl[3][r]);
                *(float4*)(er + (size_t)node * 4) =
                    make_float4(pr[0][r], pr[1][r], pr[2][r], pr[3][r]);
            }
        }
    }
}

// ---------------------------------------------------------------------------
// Kernel 3: edge weights w_t[h][e] = fp16(exp(leaky(el[src]+er[dst]))).
// ---------------------------------------------------------------------------
__global__ __launch_bounds__(256) void edgew_kernel(
    const float* __restrict__ el, const float* __restrict__ er,
    const int* __restrict__ src, const int* __restrict__ dst,
    __half* __restrict__ w_t, int E)
{
    int e = blockIdx.x * 256 + threadIdx.x;
    int hh = blockIdx.y;
    if (e >= E) return;
    int sv = src[e], dv = dst[e];
    float sc = el[sv * 4 + hh] + er[dv * 4 + hh];
    sc = sc > 0.f ? sc : NEG_SLOPE * sc;
    w_t[(size_t)hh * E + e] = __float2half(__expf(sc));
}

// ---------------------------------------------------------------------------
// Kernel 4: aggregate. One wave per node; lane l owns features 2l,2l+1.
// src indices batch-loaded coalesced (64/load) + shfl broadcast -> no loads
// on the index critical path; 8 edges (8 gathers + 4 w-dwords) in flight.
// ---------------------------------------------------------------------------
__global__ __launch_bounds__(256) void aggregate_kernel(
    const __half* __restrict__ feat, const __half* __restrict__ w_t,
    const int* __restrict__ off, const int* __restrict__ src,
    const float* __restrict__ bias, float* __restrict__ out, int N, int E)
{
    const int wid = (int)((blockIdx.x * blockDim.x + threadIdx.x) >> 6);
    const int l = threadIdx.x & 63;
    if (wid >= N) return;
    const int n = wid;
    int s = off[n];
    const int e = off[n + 1];
    const int f0 = 2 * l;
    const float b0 = bias[f0], b1 = bias[f0 + 1];
    float* outp = out + (size_t)n * 128;
    if (s >= e) {
        outp[f0] = fmaxf(b0, 0.f);
        outp[f0 + 1] = fmaxf(b1, 0.f);
        return;
    }

    const __half* wp = w_t + (size_t)(l >> 4) * E;
    float ax = 0.f, ay = 0.f, dn = 0.f;
    const unsigned int one2 = 0x3C003C00u;

    if (s & 1) {                                  // align w-stream to dword
        int sv = src[s];
        float w = __half2float(wp[s]);
        __half2 gh = *(const __half2*)(feat + (size_t)sv * 128 + f0);
        float2 fv = __half22float2(gh);
        ax += w * fv.x; ay += w * fv.y; dn += w;
        ++s;
    }

    for (int b = s; b < e; b += 64) {
        const int cnt = min(64, e - b);
        int myidx = (l < cnt) ? src[b + l] : 0;   // coalesced batch load
        int j = 0;
        for (; j + 8 <= cnt; j += 8) {
            int sv0 = __shfl(myidx, j + 0);
            int sv1 = __shfl(myidx, j + 1);
            int sv2 = __shfl(myidx, j + 2);
            int sv3 = __shfl(myidx, j + 3);
            int sv4 = __shfl(myidx, j + 4);
            int sv5 = __shfl(myidx, j + 5);
            int sv6 = __shfl(myidx, j + 6);
            int sv7 = __shfl(myidx, j + 7);
            unsigned int w2a = *(const unsigned int*)(wp + b + j);
            unsigned int w2b = *(const unsigned int*)(wp + b + j + 2);
            unsigned int w2c = *(const unsigned int*)(wp + b + j + 4);
            unsigned int w2d = *(const unsigned int*)(wp + b + j + 6);
            unsigned int g0 = *(const unsigned int*)(feat + (size_t)sv0 * 128 + f0);
            unsigned int g1 = *(const unsigned int*)(feat + (size_t)sv1 * 128 + f0);
            unsigned int g2 = *(const unsigned int*)(feat + (size_t)sv2 * 128 + f0);
            unsigned int g3 = *(const unsigned int*)(feat + (size_t)sv3 * 128 + f0);
            unsigned int g4 = *(const unsigned int*)(feat + (size_t)sv4 * 128 + f0);
            unsigned int g5 = *(const unsigned int*)(feat + (size_t)sv5 * 128 + f0);
            unsigned int g6 = *(const unsigned int*)(feat + (size_t)sv6 * 128 + f0);
            unsigned int g7 = *(const unsigned int*)(feat + (size_t)sv7 * 128 + f0);
            unsigned int lo, hi;
            lo = __builtin_amdgcn_perm(g1, g0, 0x05040100u);
            hi = __builtin_amdgcn_perm(g1, g0, 0x07060302u);
            ax = fdot2f(w2a, lo, ax); ay = fdot2f(w2a, hi, ay); dn = fdot2f(w2a, one2, dn);
            lo = __builtin_amdgcn_perm(g3, g2, 0x05040100u);
            hi = __builtin_amdgcn_perm(g3, g2, 0x07060302u);
            ax = fdot2f(w2b, lo, ax); ay = fdot2f(w2b, hi, ay); dn = fdot2f(w2b, one2, dn);
            lo = __builtin_amdgcn_perm(g5, g4, 0x05040100u);
            hi = __builtin_amdgcn_perm(g5, g4, 0x07060302u);
            ax = fdot2f(w2c, lo, ax); ay = fdot2f(w2c, hi, ay); dn = fdot2f(w2c, one2, dn);
            lo = __builtin_amdgcn_perm(g7, g6, 0x05040100u);
            hi = __builtin_amdgcn_perm(g7, g6, 0x07060302u);
            ax = fdot2f(w2d, lo, ax); ay = fdot2f(w2d, hi, ay); dn = fdot2f(w2d, one2, dn);
        }
        for (; j + 2 <= cnt; j += 2) {
            int sv0 = __shfl(myidx, j + 0);
            int sv1 = __shfl(myidx, j + 1);
            unsigned int w2 = *(const unsigned int*)(wp + b + j);
            unsigned int g0 = *(const unsigned int*)(feat + (size_t)sv0 * 128 + f0);
            unsigned int g1 = *(const unsigned int*)(feat + (size_t)sv1 * 128 + f0);
            unsigned int lo = __builtin_amdgcn_perm(g1, g0, 0x05040100u);
            unsigned int hi = __builtin_amdgcn_perm(g1, g0, 0x07060302u);
            ax = fdot2f(w2, lo, ax);
            ay = fdot2f(w2, hi, ay);
            dn = fdot2f(w2, one2, dn);
        }
        if (j < cnt) {
            int sv = __shfl(myidx, j);
            float w = __half2float(wp[b + j]);
            __half2 gh = *(const __half2*)(feat + (size_t)sv * 128 + f0);
            float2 fv = __half22float2(gh);
            ax += w * fv.x; ay += w * fv.y; dn += w;
        }
    }
    const float inv = 1.f / dn;
    *(float2*)(outp + f0) = make_float2(fmaxf(ax * inv + b0, 0.f),
                                        fmaxf(ay * inv + b1, 0.f));
}

// ---------------------------------------------------------------------------
extern "C" void kernel_launch(void* const* d_in, const int* in_sizes, int n_in,
                              void* d_out, int out_size, void* d_ws, size_t ws_size,
                              hipStream_t stream)
{
    const float* h      = (const float*)d_in[0];
    const int*   src    = (const int*)d_in[1];
    const int*   dst    = (const int*)d_in[2];
    const float* W      = (const float*)d_in[3];
    const float* attn_l = (const float*)d_in[4];
    const float* attn_r = (const float*)d_in[5];
    const float* bias   = (const float*)d_in[6];
    const int N = in_sizes[0] / 128;
    const int E = in_sizes[1];
    float* out = (float*)d_out;

    // workspace (all offsets multiples of 16B)
    char* ws = (char*)d_ws;
    __half* feat = (__half*)ws;            ws += (size_t)N * 128 * sizeof(__half); // 25.6MB
    float*  el   = (float*)ws;             ws += (size_t)N * 4 * sizeof(float);    // 1.6MB
    float*  er   = (float*)ws;             ws += (size_t)N * 4 * sizeof(float);    // 1.6MB
    __half* w_t  = (__half*)ws;            ws += (size_t)E * 4 * sizeof(__half);   // 12.8MB
    __half* w16t = (__half*)ws;            ws += 128 * 128 * sizeof(__half);       // 32KB
    int*    off  = (int*)ws;

    hipLaunchKernelGGL(seg_offsets_kernel, dim3((E + 255) / 256), dim3(256), 0, stream,
                       dst, off, E, N);
    hipLaunchKernelGGL(prep_kernel, dim3(64), dim3(256), 0, stream,
                       W, w16t);
    hipLaunchKernelGGL(proj_kernel, dim3((N + 63) / 64), dim3(256), 0, stream,
                       h, w16t, attn_l, attn_r, feat, el, er, N);
    hipLaunchKernelGGL(edgew_kernel, dim3((E + 255) / 256, 4), dim3(256), 0, stream,
                       el, er, src, dst, w_t, E);
    hipLaunchKernelGGL(aggregate_kernel, dim3((N + 3) / 4), dim3(256), 0, stream,
                       feat, w_t, off, src, bias, out, N, E);
}

// Round 6
// 112.251 us; speedup vs baseline: 1.5485x; 1.2150x over previous
//
#include <hip/hip_runtime.h>
#include <hip/hip_fp16.h>
#include <math.h>

#define NEG_SLOPE 0.2f

typedef _Float16 f16x2 __attribute__((ext_vector_type(2)));
typedef _Float16 f16x8 __attribute__((ext_vector_type(8)));
typedef float f32x4 __attribute__((ext_vector_type(4)));

__device__ __forceinline__ float fdot2f(unsigned int a, unsigned int b, float c) {
#if __has_builtin(__builtin_amdgcn_fdot2)
    return __builtin_amdgcn_fdot2(__builtin_bit_cast(f16x2, a),
                                  __builtin_bit_cast(f16x2, b), c, false);
#else
    __half2 ah = __builtin_bit_cast(__half2, a), bh = __builtin_bit_cast(__half2, b);
    float2 af = __half22float2(ah), bf = __half22float2(bh);
    return c + af.x * bf.x + af.y * bf.y;
#endif
}

// ---------------------------------------------------------------------------
// Kernel 0: segment offsets from sorted dst.
// ---------------------------------------------------------------------------
__global__ __launch_bounds__(256) void seg_offsets_kernel(
    const int* __restrict__ dst, int* __restrict__ off, int E, int N)
{
    int i = blockIdx.x * blockDim.x + threadIdx.x;
    if (i >= E) return;
    int d = dst[i];
    int prev = (i == 0) ? -1 : dst[i - 1];
    for (int n = prev + 1; n <= d; ++n) off[n] = i;
    if (i == E - 1) {
        for (int n = d + 1; n <= N; ++n) off[n] = E;
    }
}

// ---------------------------------------------------------------------------
// Kernel 1: prep — W fp32 [k][c] -> fp16 transposed [c][k].
// ---------------------------------------------------------------------------
__global__ __launch_bounds__(256) void prep_kernel(
    const float* __restrict__ W, __half* __restrict__ w16t)
{
    int tid = blockIdx.x * 256 + threadIdx.x;     // 16384 threads
    int c = tid >> 7, k = tid & 127;
    w16t[c * 128 + k] = __float2half(W[k * 128 + c]);
}

// ---------------------------------------------------------------------------
// Kernel 2: proj — feat16 = fp16(h) @ fp16(W) via MFMA 16x16x32_f16,
// fused el/er epilogue + LDS-transpose repack for coalesced feat stores.
// Block 256 thr = 4 waves; tile 64 nodes x 128 cols; K-loop 4 x 32.
// ---------------------------------------------------------------------------
__global__ __launch_bounds__(256) void proj_kernel(
    const float* __restrict__ h, const __half* __restrict__ w16t,
    const float* __restrict__ attn_l, const float* __restrict__ attn_r,
    __half* __restrict__ feat, float* __restrict__ el, float* __restrict__ er,
    int N)
{
    __shared__ __half hl[64 * 128];               // h tile, later reused as out tile
    __shared__ __half wl[128 * 128];
    const int t = threadIdx.x;
    const int nodeBase = blockIdx.x * 64;

    // stage W16t -> wl (swizzled rows: byte ^ ((row&7)<<4)); 16 chunks/col.
#pragma unroll
    for (int i = 0; i < 8; ++i) {
        int ch = t + i * 256;                     // 2048 16B chunks
        int col = ch >> 4, k8 = ch & 15;
        uint4 v = *(const uint4*)(w16t + col * 128 + k8 * 8);
        int byte = col * 256 + k8 * 16;
        *(uint4*)((char*)wl + (byte ^ ((col & 7) << 4))) = v;
    }
    // stage h (fp32 -> fp16) -> hl swizzled
#pragma unroll
    for (int i = 0; i < 8; ++i) {
        int slot = t + i * 256;                   // 2048 float4 slots
        int row = slot >> 5, c4 = slot & 31;
        int gn = nodeBase + row;
        float4 v = make_float4(0.f, 0.f, 0.f, 0.f);
        if (gn < N) v = *(const float4*)(h + (size_t)gn * 128 + c4 * 4);
        __half2 p0 = __floats2half2_rn(v.x, v.y);
        __half2 p1 = __floats2half2_rn(v.z, v.w);
        uint2 u = make_uint2(__builtin_bit_cast(unsigned int, p0),
                             __builtin_bit_cast(unsigned int, p1));
        int byte = row * 256 + c4 * 8;
        *(uint2*)((char*)hl + (byte ^ ((row & 7) << 4))) = u;
    }
    __syncthreads();

    const int l = t & 63, wave = t >> 6;
    const int arow = wave * 16 + (l & 15);
    const int kg = l >> 4;
    f32x4 acc[8];
#pragma unroll
    for (int i = 0; i < 8; ++i) acc[i] = (f32x4){0.f, 0.f, 0.f, 0.f};

#pragma unroll
    for (int kt = 0; kt < 4; ++kt) {
        const int kb = (kt * 32 + kg * 8) * 2;
        f16x8 a = *(const f16x8*)((const char*)hl +
                    ((arow * 256 + kb) ^ ((arow & 7) << 4)));
#pragma unroll
        for (int ct = 0; ct < 8; ++ct) {
            int bcol = ct * 16 + (l & 15);
            f16x8 b = *(const f16x8*)((const char*)wl +
                        ((bcol * 256 + kb) ^ ((bcol & 7) << 4)));
            acc[ct] = __builtin_amdgcn_mfma_f32_16x16x32_f16(a, b, acc[ct], 0, 0, 0);
        }
    }

    // ---- repack D-layout -> row-major fp16 tile in hl (swizzled)
    __syncthreads();                              // all waves done reading hl
    const int colLo = l & 15;
    const int rowHi = wave * 16 + (l >> 4) * 4;   // rows rowHi..rowHi+3
#pragma unroll
    for (int ct = 0; ct < 8; ++ct) {
#pragma unroll
        for (int r = 0; r < 4; ++r) {
            int row = rowHi + r;
            int byte = row * 256 + (ct * 16 + colLo) * 2;
            *(__half*)((char*)hl + (byte ^ ((row & 7) << 4))) = __float2half(acc[ct][r]);
        }
    }

    // ---- fused el/er (uses acc regs; overlaps LDS writes)
    float pl[4][4], pr[4][4];                     // [head][row]
#pragma unroll
    for (int hh = 0; hh < 4; ++hh) {
        float al0 = attn_l[hh * 32 + colLo];
        float al1 = attn_l[hh * 32 + 16 + colLo];
        float ar0 = attn_r[hh * 32 + colLo];
        float ar1 = attn_r[hh * 32 + 16 + colLo];
#pragma unroll
        for (int r = 0; r < 4; ++r) {
            pl[hh][r] = acc[2 * hh][r] * al0 + acc[2 * hh + 1][r] * al1;
            pr[hh][r] = acc[2 * hh][r] * ar0 + acc[2 * hh + 1][r] * ar1;
        }
    }
#pragma unroll
    for (int msk = 1; msk <= 8; msk <<= 1) {
#pragma unroll
        for (int hh = 0; hh < 4; ++hh)
#pragma unroll
            for (int r = 0; r < 4; ++r) {
                pl[hh][r] += __shfl_xor(pl[hh][r], msk);
                pr[hh][r] += __shfl_xor(pr[hh][r], msk);
            }
    }
    if (colLo == 0) {
#pragma unroll
        for (int r = 0; r < 4; ++r) {
            int node = nodeBase + rowHi + r;
            if (node < N) {
                *(float4*)(el + (size_t)node * 4) =
                    make_float4(pl[0][r], pl[1][r], pl[2][r], pl[3][r]);
                *(float4*)(er + (size_t)node * 4) =
                    make_float4(pr[0][r], pr[1][r], pr[2][r], pr[3][r]);
            }
        }
    }
    __syncthreads();

    // ---- coalesced feat stores: 1024 16B chunks, 4 per thread
    char* featB = (char*)feat + (size_t)nodeBase * 256;
#pragma unroll
    for (int i = 0; i < 4; ++i) {
        int c = t + i * 256;                      // chunk index
        int row = c >> 4;
        uint4 v = *(const uint4*)((const char*)hl + ((c * 16) ^ ((row & 7) << 4)));
        if (nodeBase + row < N) *(uint4*)(featB + c * 16) = v;
    }
}

// ---------------------------------------------------------------------------
// Kernel 3: edge weights, all 4 heads per thread.
// w_t[h][e] = fp16(exp(leaky(el[src][h]+er[dst][h]))).
// ---------------------------------------------------------------------------
__global__ __launch_bounds__(256) void edgew_kernel(
    const float* __restrict__ el, const float* __restrict__ er,
    const int* __restrict__ src, const int* __restrict__ dst,
    __half* __restrict__ w_t, int E)
{
    int e = blockIdx.x * 256 + threadIdx.x;
    if (e >= E) return;
    int sv = src[e], dv = dst[e];
    float4 a = *(const float4*)(el + (size_t)sv * 4);
    float4 b = *(const float4*)(er + (size_t)dv * 4);
    float s0 = a.x + b.x, s1 = a.y + b.y, s2 = a.z + b.z, s3 = a.w + b.w;
    s0 = s0 > 0.f ? s0 : NEG_SLOPE * s0;
    s1 = s1 > 0.f ? s1 : NEG_SLOPE * s1;
    s2 = s2 > 0.f ? s2 : NEG_SLOPE * s2;
    s3 = s3 > 0.f ? s3 : NEG_SLOPE * s3;
    w_t[e]                 = __float2half(__expf(s0));
    w_t[(size_t)E + e]     = __float2half(__expf(s1));
    w_t[(size_t)2 * E + e] = __float2half(__expf(s2));
    w_t[(size_t)3 * E + e] = __float2half(__expf(s3));
}

// ---------------------------------------------------------------------------
// Kernel 4: aggregate. One wave per node; lane l owns features 2l,2l+1.
// Node id forced to SGPR via readfirstlane -> src indices become s_loads
// (scalar pipe), gather addresses are SALU; VALU does only perm + fdot2.
// ---------------------------------------------------------------------------
__global__ __launch_bounds__(256) void aggregate_kernel(
    const __half* __restrict__ feat, const __half* __restrict__ w_t,
    const int* __restrict__ off, const int* __restrict__ src,
    const float* __restrict__ bias, float* __restrict__ out, int N, int E)
{
    const int wid = (int)((blockIdx.x * blockDim.x + threadIdx.x) >> 6);
    const int l = threadIdx.x & 63;
    if (wid >= N) return;
    const int n = __builtin_amdgcn_readfirstlane(wid);   // SGPR node id
    int s = off[n];                                      // s_load
    const int e = off[n + 1];                            // s_load
    const int f0 = 2 * l;
    const float b0 = bias[f0], b1 = bias[f0 + 1];
    float* outp = out + (size_t)n * 128;
    if (s >= e) {
        outp[f0] = fmaxf(b0, 0.f);
        outp[f0 + 1] = fmaxf(b1, 0.f);
        return;
    }

    const __half* wp = w_t + (size_t)(l >> 4) * E;       // per-head stream
    float ax = 0.f, ay = 0.f, dn = 0.f;
    const unsigned int one2 = 0x3C003C00u;

    if (s & 1) {                                         // align w-pairs to dword
        int sv = src[s];                                 // s_load
        float w = __half2float(wp[s]);
        __half2 gh = *(const __half2*)(feat + (size_t)sv * 128 + f0);
        float2 fv = __half22float2(gh);
        ax += w * fv.x; ay += w * fv.y; dn += w;
        ++s;
    }

    int ei = s;
    for (; ei + 8 <= e; ei += 8) {
        int sv0 = src[ei + 0], sv1 = src[ei + 1];        // s_loads (ei uniform)
        int sv2 = src[ei + 2], sv3 = src[ei + 3];
        int sv4 = src[ei + 4], sv5 = src[ei + 5];
        int sv6 = src[ei + 6], sv7 = src[ei + 7];
        const __half* wpb = wp + ei;
        unsigned int w2a = *(const unsigned int*)(wpb);
        unsigned int w2b = *(const unsigned int*)(wpb + 2);
        unsigned int w2c = *(const unsigned int*)(wpb + 4);
        unsigned int w2d = *(const unsigned int*)(wpb + 6);
        unsigned int g0 = *(const unsigned int*)(feat + (size_t)sv0 * 128 + f0);
        unsigned int g1 = *(const unsigned int*)(feat + (size_t)sv1 * 128 + f0);
        unsigned int g2 = *(const unsigned int*)(feat + (size_t)sv2 * 128 + f0);
        unsigned int g3 = *(const unsigned int*)(feat + (size_t)sv3 * 128 + f0);
        unsigned int g4 = *(const unsigned int*)(feat + (size_t)sv4 * 128 + f0);
        unsigned int g5 = *(const unsigned int*)(feat + (size_t)sv5 * 128 + f0);
        unsigned int g6 = *(const unsigned int*)(feat + (size_t)sv6 * 128 + f0);
        unsigned int g7 = *(const unsigned int*)(feat + (size_t)sv7 * 128 + f0);
        unsigned int lo, hi;
        lo = __builtin_amdgcn_perm(g1, g0, 0x05040100u);
        hi = __builtin_amdgcn_perm(g1, g0, 0x07060302u);
        ax = fdot2f(w2a, lo, ax); ay = fdot2f(w2a, hi, ay); dn = fdot2f(w2a, one2, dn);
        lo = __builtin_amdgcn_perm(g3, g2, 0x05040100u);
        hi = __builtin_amdgcn_perm(g3, g2, 0x07060302u);
        ax = fdot2f(w2b, lo, ax); ay = fdot2f(w2b, hi, ay); dn = fdot2f(w2b, one2, dn);
        lo = __builtin_amdgcn_perm(g5, g4, 0x05040100u);
        hi = __builtin_amdgcn_perm(g5, g4, 0x07060302u);
        ax = fdot2f(w2c, lo, ax); ay = fdot2f(w2c, hi, ay); dn = fdot2f(w2c, one2, dn);
        lo = __builtin_amdgcn_perm(g7, g6, 0x05040100u);
        hi = __builtin_amdgcn_perm(g7, g6, 0x07060302u);
        ax = fdot2f(w2d, lo, ax); ay = fdot2f(w2d, hi, ay); dn = fdot2f(w2d, one2, dn);
    }
    for (; ei + 2 <= e; ei += 2) {
        int sv0 = src[ei + 0], sv1 = src[ei + 1];
        unsigned int w2 = *(const unsigned int*)(wp + ei);
        unsigned int g0 = *(const unsigned int*)(feat + (size_t)sv0 * 128 + f0);
        unsigned int g1 = *(const unsigned int*)(feat + (size_t)sv1 * 128 + f0);
        unsigned int lo = __builtin_amdgcn_perm(g1, g0, 0x05040100u);
        unsigned int hi = __builtin_amdgcn_perm(g1, g0, 0x07060302u);
        ax = fdot2f(w2, lo, ax);
        ay = fdot2f(w2, hi, ay);
        dn = fdot2f(w2, one2, dn);
    }
    if (ei < e) {
        int sv = src[ei];
        float w = __half2float(wp[ei]);
        __half2 gh = *(const __half2*)(feat + (size_t)sv * 128 + f0);
        float2 fv = __half22float2(gh);
        ax += w * fv.x; ay += w * fv.y; dn += w;
    }
    const float inv = 1.f / dn;
    *(float2*)(outp + f0) = make_float2(fmaxf(ax * inv + b0, 0.f),
                                        fmaxf(ay * inv + b1, 0.f));
}

// ---------------------------------------------------------------------------
extern "C" void kernel_launch(void* const* d_in, const int* in_sizes, int n_in,
                              void* d_out, int out_size, void* d_ws, size_t ws_size,
                              hipStream_t stream)
{
    const float* h      = (const float*)d_in[0];
    const int*   src    = (const int*)d_in[1];
    const int*   dst    = (const int*)d_in[2];
    const float* W      = (const float*)d_in[3];
    const float* attn_l = (const float*)d_in[4];
    const float* attn_r = (const float*)d_in[5];
    const float* bias   = (const float*)d_in[6];
    const int N = in_sizes[0] / 128;
    const int E = in_sizes[1];
    float* out = (float*)d_out;

    // workspace (all offsets multiples of 16B)
    char* ws = (char*)d_ws;
    __half* feat = (__half*)ws;            ws += (size_t)N * 128 * sizeof(__half); // 25.6MB
    float*  el   = (float*)ws;             ws += (size_t)N * 4 * sizeof(float);    // 1.6MB
    float*  er   = (float*)ws;             ws += (size_t)N * 4 * sizeof(float);    // 1.6MB
    __half* w_t  = (__half*)ws;            ws += (size_t)E * 4 * sizeof(__half);   // 12.8MB
    __half* w16t = (__half*)ws;            ws += 128 * 128 * sizeof(__half);       // 32KB
    int*    off  = (int*)ws;

    hipLaunchKernelGGL(seg_offsets_kernel, dim3((E + 255) / 256), dim3(256), 0, stream,
                       dst, off, E, N);
    hipLaunchKernelGGL(prep_kernel, dim3(64), dim3(256), 0, stream,
                       W, w16t);
    hipLaunchKernelGGL(proj_kernel, dim3((N + 63) / 64), dim3(256), 0, stream,
                       h, w16t, attn_l, attn_r, feat, el, er, N);
    hipLaunchKernelGGL(edgew_kernel, dim3((E + 255) / 256), dim3(256), 0, stream,
                       el, er, src, dst, w_t, E);
    hipLaunchKernelGGL(aggregate_kernel, dim3((N + 3) / 4), dim3(256), 0, stream,
                       feat, w_t, off, src, bias, out, N, E);
}

// Round 7
// 110.127 us; speedup vs baseline: 1.5783x; 1.0193x over previous
//
#include <hip/hip_runtime.h>
#include <hip/hip_fp16.h>
#include <math.h>

#define NEG_SLOPE 0.2f

typedef _Float16 f16x2 __attribute__((ext_vector_type(2)));
typedef _Float16 f16x8 __attribute__((ext_vector_type(8)));
typedef float f32x4 __attribute__((ext_vector_type(4)));

__device__ __forceinline__ float fdot2f(unsigned int a, unsigned int b, float c) {
#if __has_builtin(__builtin_amdgcn_fdot2)
    return __builtin_amdgcn_fdot2(__builtin_bit_cast(f16x2, a),
                                  __builtin_bit_cast(f16x2, b), c, false);
#else
    __half2 ah = __builtin_bit_cast(__half2, a), bh = __builtin_bit_cast(__half2, b);
    float2 af = __half22float2(ah), bf = __half22float2(bh);
    return c + af.x * bf.x + af.y * bf.y;
#endif
}

// ---------------------------------------------------------------------------
// Kernel 0: fused prep (blocks 0..63) + segment offsets (blocks 64..).
// ---------------------------------------------------------------------------
__global__ __launch_bounds__(256) void prep_seg_kernel(
    const float* __restrict__ W, __half* __restrict__ w16t,
    const int* __restrict__ dst, int* __restrict__ off, int E, int N)
{
    const int b = blockIdx.x;
    if (b < 64) {                                  // W fp32 [k][c] -> fp16 [c][k]
        int tid = b * 256 + threadIdx.x;
        int c = tid >> 7, k = tid & 127;
        w16t[c * 128 + k] = __float2half(W[k * 128 + c]);
        return;
    }
    int i = (b - 64) * 256 + threadIdx.x;
    if (i >= E) return;
    int d = dst[i];
    int prev = (i == 0) ? -1 : dst[i - 1];
    for (int n = prev + 1; n <= d; ++n) off[n] = i;
    if (i == E - 1) {
        for (int n = d + 1; n <= N; ++n) off[n] = E;
    }
}

// ---------------------------------------------------------------------------
// Kernel 1: proj — feat16 = fp16(h) @ fp16(W) via MFMA 16x16x32_f16,
// fused el/er epilogue + LDS-transpose repack for coalesced feat stores.
// ---------------------------------------------------------------------------
__global__ __launch_bounds__(256) void proj_kernel(
    const float* __restrict__ h, const __half* __restrict__ w16t,
    const float* __restrict__ attn_l, const float* __restrict__ attn_r,
    __half* __restrict__ feat, float* __restrict__ el, float* __restrict__ er,
    int N)
{
    __shared__ __half hl[64 * 128];               // h tile, later reused as out tile
    __shared__ __half wl[128 * 128];
    const int t = threadIdx.x;
    const int nodeBase = blockIdx.x * 64;

#pragma unroll
    for (int i = 0; i < 8; ++i) {
        int ch = t + i * 256;                     // 2048 16B chunks
        int col = ch >> 4, k8 = ch & 15;
        uint4 v = *(const uint4*)(w16t + col * 128 + k8 * 8);
        int byte = col * 256 + k8 * 16;
        *(uint4*)((char*)wl + (byte ^ ((col & 7) << 4))) = v;
    }
#pragma unroll
    for (int i = 0; i < 8; ++i) {
        int slot = t + i * 256;                   // 2048 float4 slots
        int row = slot >> 5, c4 = slot & 31;
        int gn = nodeBase + row;
        float4 v = make_float4(0.f, 0.f, 0.f, 0.f);
        if (gn < N) v = *(const float4*)(h + (size_t)gn * 128 + c4 * 4);
        __half2 p0 = __floats2half2_rn(v.x, v.y);
        __half2 p1 = __floats2half2_rn(v.z, v.w);
        uint2 u = make_uint2(__builtin_bit_cast(unsigned int, p0),
                             __builtin_bit_cast(unsigned int, p1));
        int byte = row * 256 + c4 * 8;
        *(uint2*)((char*)hl + (byte ^ ((row & 7) << 4))) = u;
    }
    __syncthreads();

    const int l = t & 63, wave = t >> 6;
    const int arow = wave * 16 + (l & 15);
    const int kg = l >> 4;
    f32x4 acc[8];
#pragma unroll
    for (int i = 0; i < 8; ++i) acc[i] = (f32x4){0.f, 0.f, 0.f, 0.f};

#pragma unroll
    for (int kt = 0; kt < 4; ++kt) {
        const int kb = (kt * 32 + kg * 8) * 2;
        f16x8 a = *(const f16x8*)((const char*)hl +
                    ((arow * 256 + kb) ^ ((arow & 7) << 4)));
#pragma unroll
        for (int ct = 0; ct < 8; ++ct) {
            int bcol = ct * 16 + (l & 15);
            f16x8 b = *(const f16x8*)((const char*)wl +
                        ((bcol * 256 + kb) ^ ((bcol & 7) << 4)));
            acc[ct] = __builtin_amdgcn_mfma_f32_16x16x32_f16(a, b, acc[ct], 0, 0, 0);
        }
    }

    __syncthreads();                              // all waves done reading hl
    const int colLo = l & 15;
    const int rowHi = wave * 16 + (l >> 4) * 4;
#pragma unroll
    for (int ct = 0; ct < 8; ++ct) {
#pragma unroll
        for (int r = 0; r < 4; ++r) {
            int row = rowHi + r;
            int byte = row * 256 + (ct * 16 + colLo) * 2;
            *(__half*)((char*)hl + (byte ^ ((row & 7) << 4))) = __float2half(acc[ct][r]);
        }
    }

    float pl[4][4], pr[4][4];                     // [head][row]
#pragma unroll
    for (int hh = 0; hh < 4; ++hh) {
        float al0 = attn_l[hh * 32 + colLo];
        float al1 = attn_l[hh * 32 + 16 + colLo];
        float ar0 = attn_r[hh * 32 + colLo];
        float ar1 = attn_r[hh * 32 + 16 + colLo];
#pragma unroll
        for (int r = 0; r < 4; ++r) {
            pl[hh][r] = acc[2 * hh][r] * al0 + acc[2 * hh + 1][r] * al1;
            pr[hh][r] = acc[2 * hh][r] * ar0 + acc[2 * hh + 1][r] * ar1;
        }
    }
#pragma unroll
    for (int msk = 1; msk <= 8; msk <<= 1) {
#pragma unroll
        for (int hh = 0; hh < 4; ++hh)
#pragma unroll
            for (int r = 0; r < 4; ++r) {
                pl[hh][r] += __shfl_xor(pl[hh][r], msk);
                pr[hh][r] += __shfl_xor(pr[hh][r], msk);
            }
    }
    if (colLo == 0) {
#pragma unroll
        for (int r = 0; r < 4; ++r) {
            int node = nodeBase + rowHi + r;
            if (node < N) {
                *(float4*)(el + (size_t)node * 4) =
                    make_float4(pl[0][r], pl[1][r], pl[2][r], pl[3][r]);
                *(float4*)(er + (size_t)node * 4) =
                    make_float4(pr[0][r], pr[1][r], pr[2][r], pr[3][r]);
            }
        }
    }
    __syncthreads();

    char* featB = (char*)feat + (size_t)nodeBase * 256;
#pragma unroll
    for (int i = 0; i < 4; ++i) {
        int c = t + i * 256;
        int row = c >> 4;
        uint4 v = *(const uint4*)((const char*)hl + ((c * 16) ^ ((row & 7) << 4)));
        if (nodeBase + row < N) *(uint4*)(featB + c * 16) = v;
    }
}

// ---------------------------------------------------------------------------
// Kernel 2: edge weights, all 4 heads per thread.
// ---------------------------------------------------------------------------
__global__ __launch_bounds__(256) void edgew_kernel(
    const float* __restrict__ el, const float* __restrict__ er,
    const int* __restrict__ src, const int* __restrict__ dst,
    __half* __restrict__ w_t, int E)
{
    int e = blockIdx.x * 256 + threadIdx.x;
    if (e >= E) return;
    int sv = src[e], dv = dst[e];
    float4 a = *(const float4*)(el + (size_t)sv * 4);
    float4 b = *(const float4*)(er + (size_t)dv * 4);
    float s0 = a.x + b.x, s1 = a.y + b.y, s2 = a.z + b.z, s3 = a.w + b.w;
    s0 = s0 > 0.f ? s0 : NEG_SLOPE * s0;
    s1 = s1 > 0.f ? s1 : NEG_SLOPE * s1;
    s2 = s2 > 0.f ? s2 : NEG_SLOPE * s2;
    s3 = s3 > 0.f ? s3 : NEG_SLOPE * s3;
    w_t[e]                 = __float2half(__expf(s0));
    w_t[(size_t)E + e]     = __float2half(__expf(s1));
    w_t[(size_t)2 * E + e] = __float2half(__expf(s2));
    w_t[(size_t)3 * E + e] = __float2half(__expf(s3));
}

// ---------------------------------------------------------------------------
// Kernel 3: aggregate. One wave per node; lane l owns features 2l,2l+1.
// Scalar-pipe indices (node id in SGPR -> src[] are s_loads); 16 feature
// gathers + 8 w-dwords in flight per iteration; remainder ladder 8/4/2/1.
// ---------------------------------------------------------------------------
__global__ __launch_bounds__(256) void aggregate_kernel(
    const __half* __restrict__ feat, const __half* __restrict__ w_t,
    const int* __restrict__ off, const int* __restrict__ src,
    const float* __restrict__ bias, float* __restrict__ out, int N, int E)
{
    const int wid = (int)((blockIdx.x * blockDim.x + threadIdx.x) >> 6);
    const int l = threadIdx.x & 63;
    if (wid >= N) return;
    const int n = __builtin_amdgcn_readfirstlane(wid);   // SGPR node id
    int s = off[n];                                      // s_load
    const int e = off[n + 1];                            // s_load
    const int f0 = 2 * l;
    const float b0 = bias[f0], b1 = bias[f0 + 1];
    float* outp = out + (size_t)n * 128;
    if (s >= e) {
        outp[f0] = fmaxf(b0, 0.f);
        outp[f0 + 1] = fmaxf(b1, 0.f);
        return;
    }

    const __half* wp = w_t + (size_t)(l >> 4) * E;       // per-head stream
    float ax = 0.f, ay = 0.f, dn = 0.f;
    const unsigned int one2 = 0x3C003C00u;

    if (s & 1) {                                         // align w-pairs to dword
        int sv = src[s];
        float w = __half2float(wp[s]);
        __half2 gh = *(const __half2*)(feat + (size_t)sv * 128 + f0);
        float2 fv = __half22float2(gh);
        ax += w * fv.x; ay += w * fv.y; dn += w;
        ++s;
    }

    int ei = s;
    for (; ei + 16 <= e; ei += 16) {                     // 16 gathers in flight
        int sv[16];
#pragma unroll
        for (int k = 0; k < 16; ++k) sv[k] = src[ei + k];
        unsigned int w2[8];
#pragma unroll
        for (int k = 0; k < 8; ++k) w2[k] = *(const unsigned int*)(wp + ei + 2 * k);
        unsigned int g[16];
#pragma unroll
        for (int k = 0; k < 16; ++k)
            g[k] = *(const unsigned int*)(feat + (size_t)sv[k] * 128 + f0);
#pragma unroll
        for (int k = 0; k < 8; ++k) {
            unsigned int lo = __builtin_amdgcn_perm(g[2 * k + 1], g[2 * k], 0x05040100u);
            unsigned int hi = __builtin_amdgcn_perm(g[2 * k + 1], g[2 * k], 0x07060302u);
            ax = fdot2f(w2[k], lo, ax);
            ay = fdot2f(w2[k], hi, ay);
            dn = fdot2f(w2[k], one2, dn);
        }
    }
    if (ei + 8 <= e) {
        int sv[8];
#pragma unroll
        for (int k = 0; k < 8; ++k) sv[k] = src[ei + k];
        unsigned int w2[4];
#pragma unroll
        for (int k = 0; k < 4; ++k) w2[k] = *(const unsigned int*)(wp + ei + 2 * k);
        unsigned int g[8];
#pragma unroll
        for (int k = 0; k < 8; ++k)
            g[k] = *(const unsigned int*)(feat + (size_t)sv[k] * 128 + f0);
#pragma unroll
        for (int k = 0; k < 4; ++k) {
            unsigned int lo = __builtin_amdgcn_perm(g[2 * k + 1], g[2 * k], 0x05040100u);
            unsigned int hi = __builtin_amdgcn_perm(g[2 * k + 1], g[2 * k], 0x07060302u);
            ax = fdot2f(w2[k], lo, ax);
            ay = fdot2f(w2[k], hi, ay);
            dn = fdot2f(w2[k], one2, dn);
        }
        ei += 8;
    }
    if (ei + 4 <= e) {
        int sv0 = src[ei], sv1 = src[ei + 1], sv2 = src[ei + 2], sv3 = src[ei + 3];
        unsigned int w2a = *(const unsigned int*)(wp + ei);
        unsigned int w2b = *(const unsigned int*)(wp + ei + 2);
        unsigned int g0 = *(const unsigned int*)(feat + (size_t)sv0 * 128 + f0);
        unsigned int g1 = *(const unsigned int*)(feat + (size_t)sv1 * 128 + f0);
        unsigned int g2 = *(const unsigned int*)(feat + (size_t)sv2 * 128 + f0);
        unsigned int g3 = *(const unsigned int*)(feat + (size_t)sv3 * 128 + f0);
        unsigned int lo = __builtin_amdgcn_perm(g1, g0, 0x05040100u);
        unsigned int hi = __builtin_amdgcn_perm(g1, g0, 0x07060302u);
        ax = fdot2f(w2a, lo, ax); ay = fdot2f(w2a, hi, ay); dn = fdot2f(w2a, one2, dn);
        lo = __builtin_amdgcn_perm(g3, g2, 0x05040100u);
        hi = __builtin_amdgcn_perm(g3, g2, 0x07060302u);
        ax = fdot2f(w2b, lo, ax); ay = fdot2f(w2b, hi, ay); dn = fdot2f(w2b, one2, dn);
        ei += 4;
    }
    if (ei + 2 <= e) {
        int sv0 = src[ei], sv1 = src[ei + 1];
        unsigned int w2 = *(const unsigned int*)(wp + ei);
        unsigned int g0 = *(const unsigned int*)(feat + (size_t)sv0 * 128 + f0);
        unsigned int g1 = *(const unsigned int*)(feat + (size_t)sv1 * 128 + f0);
        unsigned int lo = __builtin_amdgcn_perm(g1, g0, 0x05040100u);
        unsigned int hi = __builtin_amdgcn_perm(g1, g0, 0x07060302u);
        ax = fdot2f(w2, lo, ax); ay = fdot2f(w2, hi, ay); dn = fdot2f(w2, one2, dn);
        ei += 2;
    }
    if (ei < e) {
        int sv = src[ei];
        float w = __half2float(wp[ei]);
        __half2 gh = *(const __half2*)(feat + (size_t)sv * 128 + f0);
        float2 fv = __half22float2(gh);
        ax += w * fv.x; ay += w * fv.y; dn += w;
    }
    const float inv = 1.f / dn;
    *(float2*)(outp + f0) = make_float2(fmaxf(ax * inv + b0, 0.f),
                                        fmaxf(ay * inv + b1, 0.f));
}

// ---------------------------------------------------------------------------
extern "C" void kernel_launch(void* const* d_in, const int* in_sizes, int n_in,
                              void* d_out, int out_size, void* d_ws, size_t ws_size,
                              hipStream_t stream)
{
    const float* h      = (const float*)d_in[0];
    const int*   src    = (const int*)d_in[1];
    const int*   dst    = (const int*)d_in[2];
    const float* W      = (const float*)d_in[3];
    const float* attn_l = (const float*)d_in[4];
    const float* attn_r = (const float*)d_in[5];
    const float* bias   = (const float*)d_in[6];
    const int N = in_sizes[0] / 128;
    const int E = in_sizes[1];
    float* out = (float*)d_out;

    // workspace (all offsets multiples of 16B)
    char* ws = (char*)d_ws;
    __half* feat = (__half*)ws;            ws += (size_t)N * 128 * sizeof(__half); // 25.6MB
    float*  el   = (float*)ws;             ws += (size_t)N * 4 * sizeof(float);    // 1.6MB
    float*  er   = (float*)ws;             ws += (size_t)N * 4 * sizeof(float);    // 1.6MB
    __half* w_t  = (__half*)ws;            ws += (size_t)E * 4 * sizeof(__half);   // 12.8MB
    __half* w16t = (__half*)ws;            ws += 128 * 128 * sizeof(__half);       // 32KB
    int*    off  = (int*)ws;

    hipLaunchKernelGGL(prep_seg_kernel, dim3(64 + (E + 255) / 256), dim3(256), 0, stream,
                       W, w16t, dst, off, E, N);
    hipLaunchKernelGGL(proj_kernel, dim3((N + 63) / 64), dim3(256), 0, stream,
                       h, w16t, attn_l, attn_r, feat, el, er, N);
    hipLaunchKernelGGL(edgew_kernel, dim3((E + 255) / 256), dim3(256), 0, stream,
                       el, er, src, dst, w_t, E);
    hipLaunchKernelGGL(aggregate_kernel, dim3((N + 3) / 4), dim3(256), 0, stream,
                       feat, w_t, off, src, bias, out, N, E);
}

// Round 8
// 108.914 us; speedup vs baseline: 1.5959x; 1.0111x over previous
//
#include <hip/hip_runtime.h>
#include <hip/hip_fp16.h>
#include <math.h>

#define NEG_SLOPE 0.2f

typedef _Float16 f16x2 __attribute__((ext_vector_type(2)));
typedef _Float16 f16x8 __attribute__((ext_vector_type(8)));
typedef float f32x4 __attribute__((ext_vector_type(4)));

__device__ __forceinline__ float fdot2f(unsigned int a, unsigned int b, float c) {
#if __has_builtin(__builtin_amdgcn_fdot2)
    return __builtin_amdgcn_fdot2(__builtin_bit_cast(f16x2, a),
                                  __builtin_bit_cast(f16x2, b), c, false);
#else
    __half2 ah = __builtin_bit_cast(__half2, a), bh = __builtin_bit_cast(__half2, b);
    float2 af = __half22float2(ah), bf = __half22float2(bh);
    return c + af.x * bf.x + af.y * bf.y;
#endif
}

__device__ __forceinline__ unsigned int packw(float a, float b) {
#if __has_builtin(__builtin_amdgcn_cvt_pkrtz)
    return __builtin_bit_cast(unsigned int, __builtin_amdgcn_cvt_pkrtz(a, b));
#else
    return __builtin_bit_cast(unsigned int, __floats2half2_rn(a, b));
#endif
}

// ---------------------------------------------------------------------------
// Kernel 0: fused prep (blocks 0..63) + segment offsets (blocks 64..).
// ---------------------------------------------------------------------------
__global__ __launch_bounds__(256) void prep_seg_kernel(
    const float* __restrict__ W, __half* __restrict__ w16t,
    const int* __restrict__ dst, int* __restrict__ off, int E, int N)
{
    const int b = blockIdx.x;
    if (b < 64) {                                  // W fp32 [k][c] -> fp16 [c][k]
        int tid = b * 256 + threadIdx.x;
        int c = tid >> 7, k = tid & 127;
        w16t[c * 128 + k] = __float2half(W[k * 128 + c]);
        return;
    }
    int i = (b - 64) * 256 + threadIdx.x;
    if (i >= E) return;
    int d = dst[i];
    int prev = (i == 0) ? -1 : dst[i - 1];
    for (int n = prev + 1; n <= d; ++n) off[n] = i;
    if (i == E - 1) {
        for (int n = d + 1; n <= N; ++n) off[n] = E;
    }
}

// ---------------------------------------------------------------------------
// Kernel 1: proj — feat16 = fp16(h) @ fp16(W) via MFMA 16x16x32_f16,
// fused el/er epilogue + LDS-transpose repack for coalesced feat stores.
// ---------------------------------------------------------------------------
__global__ __launch_bounds__(256) void proj_kernel(
    const float* __restrict__ h, const __half* __restrict__ w16t,
    const float* __restrict__ attn_l, const float* __restrict__ attn_r,
    __half* __restrict__ feat, float* __restrict__ el, float* __restrict__ er,
    int N)
{
    __shared__ __half hl[64 * 128];               // h tile, later reused as out tile
    __shared__ __half wl[128 * 128];
    const int t = threadIdx.x;
    const int nodeBase = blockIdx.x * 64;

#pragma unroll
    for (int i = 0; i < 8; ++i) {
        int ch = t + i * 256;                     // 2048 16B chunks
        int col = ch >> 4, k8 = ch & 15;
        uint4 v = *(const uint4*)(w16t + col * 128 + k8 * 8);
        int byte = col * 256 + k8 * 16;
        *(uint4*)((char*)wl + (byte ^ ((col & 7) << 4))) = v;
    }
#pragma unroll
    for (int i = 0; i < 8; ++i) {
        int slot = t + i * 256;                   // 2048 float4 slots
        int row = slot >> 5, c4 = slot & 31;
        int gn = nodeBase + row;
        float4 v = make_float4(0.f, 0.f, 0.f, 0.f);
        if (gn < N) v = *(const float4*)(h + (size_t)gn * 128 + c4 * 4);
        __half2 p0 = __floats2half2_rn(v.x, v.y);
        __half2 p1 = __floats2half2_rn(v.z, v.w);
        uint2 u = make_uint2(__builtin_bit_cast(unsigned int, p0),
                             __builtin_bit_cast(unsigned int, p1));
        int byte = row * 256 + c4 * 8;
        *(uint2*)((char*)hl + (byte ^ ((row & 7) << 4))) = u;
    }
    __syncthreads();

    const int l = t & 63, wave = t >> 6;
    const int arow = wave * 16 + (l & 15);
    const int kg = l >> 4;
    f32x4 acc[8];
#pragma unroll
    for (int i = 0; i < 8; ++i) acc[i] = (f32x4){0.f, 0.f, 0.f, 0.f};

#pragma unroll
    for (int kt = 0; kt < 4; ++kt) {
        const int kb = (kt * 32 + kg * 8) * 2;
        f16x8 a = *(const f16x8*)((const char*)hl +
                    ((arow * 256 + kb) ^ ((arow & 7) << 4)));
#pragma unroll
        for (int ct = 0; ct < 8; ++ct) {
            int bcol = ct * 16 + (l & 15);
            f16x8 b = *(const f16x8*)((const char*)wl +
                        ((bcol * 256 + kb) ^ ((bcol & 7) << 4)));
            acc[ct] = __builtin_amdgcn_mfma_f32_16x16x32_f16(a, b, acc[ct], 0, 0, 0);
        }
    }

    __syncthreads();                              // all waves done reading hl
    const int colLo = l & 15;
    const int rowHi = wave * 16 + (l >> 4) * 4;
#pragma unroll
    for (int ct = 0; ct < 8; ++ct) {
#pragma unroll
        for (int r = 0; r < 4; ++r) {
            int row = rowHi + r;
            int byte = row * 256 + (ct * 16 + colLo) * 2;
            *(__half*)((char*)hl + (byte ^ ((row & 7) << 4))) = __float2half(acc[ct][r]);
        }
    }

    float pl[4][4], pr[4][4];                     // [head][row]
#pragma unroll
    for (int hh = 0; hh < 4; ++hh) {
        float al0 = attn_l[hh * 32 + colLo];
        float al1 = attn_l[hh * 32 + 16 + colLo];
        float ar0 = attn_r[hh * 32 + colLo];
        float ar1 = attn_r[hh * 32 + 16 + colLo];
#pragma unroll
        for (int r = 0; r < 4; ++r) {
            pl[hh][r] = acc[2 * hh][r] * al0 + acc[2 * hh + 1][r] * al1;
            pr[hh][r] = acc[2 * hh][r] * ar0 + acc[2 * hh + 1][r] * ar1;
        }
    }
#pragma unroll
    for (int msk = 1; msk <= 8; msk <<= 1) {
#pragma unroll
        for (int hh = 0; hh < 4; ++hh)
#pragma unroll
            for (int r = 0; r < 4; ++r) {
                pl[hh][r] += __shfl_xor(pl[hh][r], msk);
                pr[hh][r] += __shfl_xor(pr[hh][r], msk);
            }
    }
    if (colLo == 0) {
#pragma unroll
        for (int r = 0; r < 4; ++r) {
            int node = nodeBase + rowHi + r;
            if (node < N) {
                *(float4*)(el + (size_t)node * 4) =
                    make_float4(pl[0][r], pl[1][r], pl[2][r], pl[3][r]);
                *(float4*)(er + (size_t)node * 4) =
                    make_float4(pr[0][r], pr[1][r], pr[2][r], pr[3][r]);
            }
        }
    }
    __syncthreads();

    char* featB = (char*)feat + (size_t)nodeBase * 256;
#pragma unroll
    for (int i = 0; i < 4; ++i) {
        int c = t + i * 256;
        int row = c >> 4;
        uint4 v = *(const uint4*)((const char*)hl + ((c * 16) ^ ((row & 7) << 4)));
        if (nodeBase + row < N) *(uint4*)(featB + c * 16) = v;
    }
}

// ---------------------------------------------------------------------------
// Kernel 2: fused aggregate. One wave per node; lane l owns features 2l,2l+1
// (head hm = l>>4). Edge weights computed inline: el[src] is an L2-resident
// 16B-segment load (src index in SGPR), exp/pack on the idle VALU; the w_t
// intermediate (12.8MB write + 12.8MB read) is gone.
// ---------------------------------------------------------------------------
__global__ __launch_bounds__(256) void aggregate_kernel(
    const __half* __restrict__ feat, const float* __restrict__ el,
    const float* __restrict__ er, const int* __restrict__ off,
    const int* __restrict__ src, const float* __restrict__ bias,
    float* __restrict__ out, int N)
{
    const int wid = (int)((blockIdx.x * blockDim.x + threadIdx.x) >> 6);
    const int l = threadIdx.x & 63;
    if (wid >= N) return;
    const int n = __builtin_amdgcn_readfirstlane(wid);   // SGPR node id
    const int s = off[n];                                // s_load
    const int e = off[n + 1];                            // s_load
    const int f0 = 2 * l;
    const int hm = l >> 4;
    const float b0 = bias[f0], b1 = bias[f0 + 1];
    float* outp = out + (size_t)n * 128;
    if (s >= e) {
        outp[f0] = fmaxf(b0, 0.f);
        outp[f0 + 1] = fmaxf(b1, 0.f);
        return;
    }

    const float er_mine = er[n * 4 + hm];                // one 16B segment/wave
    float ax = 0.f, ay = 0.f, dn = 0.f;
    const unsigned int one2 = 0x3C003C00u;

    int ei = s;
    for (; ei + 16 <= e; ei += 16) {
        int sv[16];
#pragma unroll
        for (int k = 0; k < 16; ++k) sv[k] = src[ei + k];        // s_loads
        float elv[16];
#pragma unroll
        for (int k = 0; k < 16; ++k) elv[k] = el[(size_t)sv[k] * 4 + hm];
        unsigned int g[16];
#pragma unroll
        for (int k = 0; k < 16; ++k)
            g[k] = *(const unsigned int*)(feat + (size_t)sv[k] * 128 + f0);
        float w[16];
#pragma unroll
        for (int k = 0; k < 16; ++k) {
            float sc = elv[k] + er_mine;
            sc = sc > 0.f ? sc : NEG_SLOPE * sc;
            w[k] = __expf(sc);
        }
#pragma unroll
        for (int k = 0; k < 8; ++k) {
            unsigned int w2 = packw(w[2 * k], w[2 * k + 1]);
            unsigned int lo = __builtin_amdgcn_perm(g[2 * k + 1], g[2 * k], 0x05040100u);
            unsigned int hi = __builtin_amdgcn_perm(g[2 * k + 1], g[2 * k], 0x07060302u);
            ax = fdot2f(w2, lo, ax);
            ay = fdot2f(w2, hi, ay);
            dn = fdot2f(w2, one2, dn);
        }
    }
    if (ei + 8 <= e) {
        int sv[8];
#pragma unroll
        for (int k = 0; k < 8; ++k) sv[k] = src[ei + k];
        float elv[8];
#pragma unroll
        for (int k = 0; k < 8; ++k) elv[k] = el[(size_t)sv[k] * 4 + hm];
        unsigned int g[8];
#pragma unroll
        for (int k = 0; k < 8; ++k)
            g[k] = *(const unsigned int*)(feat + (size_t)sv[k] * 128 + f0);
        float w[8];
#pragma unroll
        for (int k = 0; k < 8; ++k) {
            float sc = elv[k] + er_mine;
            sc = sc > 0.f ? sc : NEG_SLOPE * sc;
            w[k] = __expf(sc);
        }
#pragma unroll
        for (int k = 0; k < 4; ++k) {
            unsigned int w2 = packw(w[2 * k], w[2 * k + 1]);
            unsigned int lo = __builtin_amdgcn_perm(g[2 * k + 1], g[2 * k], 0x05040100u);
            unsigned int hi = __builtin_amdgcn_perm(g[2 * k + 1], g[2 * k], 0x07060302u);
            ax = fdot2f(w2, lo, ax);
            ay = fdot2f(w2, hi, ay);
            dn = fdot2f(w2, one2, dn);
        }
        ei += 8;
    }
    if (ei + 4 <= e) {
        int sv0 = src[ei], sv1 = src[ei + 1], sv2 = src[ei + 2], sv3 = src[ei + 3];
        float e0 = el[(size_t)sv0 * 4 + hm], e1 = el[(size_t)sv1 * 4 + hm];
        float e2 = el[(size_t)sv2 * 4 + hm], e3 = el[(size_t)sv3 * 4 + hm];
        unsigned int g0 = *(const unsigned int*)(feat + (size_t)sv0 * 128 + f0);
        unsigned int g1 = *(const unsigned int*)(feat + (size_t)sv1 * 128 + f0);
        unsigned int g2 = *(const unsigned int*)(feat + (size_t)sv2 * 128 + f0);
        unsigned int g3 = *(const unsigned int*)(feat + (size_t)sv3 * 128 + f0);
        float s0 = e0 + er_mine, s1 = e1 + er_mine, s2 = e2 + er_mine, s3 = e3 + er_mine;
        s0 = s0 > 0.f ? s0 : NEG_SLOPE * s0;
        s1 = s1 > 0.f ? s1 : NEG_SLOPE * s1;
        s2 = s2 > 0.f ? s2 : NEG_SLOPE * s2;
        s3 = s3 > 0.f ? s3 : NEG_SLOPE * s3;
        unsigned int w2a = packw(__expf(s0), __expf(s1));
        unsigned int w2b = packw(__expf(s2), __expf(s3));
        unsigned int lo = __builtin_amdgcn_perm(g1, g0, 0x05040100u);
        unsigned int hi = __builtin_amdgcn_perm(g1, g0, 0x07060302u);
        ax = fdot2f(w2a, lo, ax); ay = fdot2f(w2a, hi, ay); dn = fdot2f(w2a, one2, dn);
        lo = __builtin_amdgcn_perm(g3, g2, 0x05040100u);
        hi = __builtin_amdgcn_perm(g3, g2, 0x07060302u);
        ax = fdot2f(w2b, lo, ax); ay = fdot2f(w2b, hi, ay); dn = fdot2f(w2b, one2, dn);
        ei += 4;
    }
    for (; ei < e; ++ei) {                               // <=3 tail edges
        int sv = src[ei];
        float sc = el[(size_t)sv * 4 + hm] + er_mine;
        sc = sc > 0.f ? sc : NEG_SLOPE * sc;
        float w = __expf(sc);
        __half2 gh = *(const __half2*)(feat + (size_t)sv * 128 + f0);
        float2 fv = __half22float2(gh);
        ax += w * fv.x; ay += w * fv.y; dn += w;
    }
    const float inv = 1.f / dn;
    *(float2*)(outp + f0) = make_float2(fmaxf(ax * inv + b0, 0.f),
                                        fmaxf(ay * inv + b1, 0.f));
}

// ---------------------------------------------------------------------------
extern "C" void kernel_launch(void* const* d_in, const int* in_sizes, int n_in,
                              void* d_out, int out_size, void* d_ws, size_t ws_size,
                              hipStream_t stream)
{
    const float* h      = (const float*)d_in[0];
    const int*   src    = (const int*)d_in[1];
    const int*   dst    = (const int*)d_in[2];
    const float* W      = (const float*)d_in[3];
    const float* attn_l = (const float*)d_in[4];
    const float* attn_r = (const float*)d_in[5];
    const float* bias   = (const float*)d_in[6];
    const int N = in_sizes[0] / 128;
    const int E = in_sizes[1];
    float* out = (float*)d_out;

    // workspace (all offsets multiples of 16B)
    char* ws = (char*)d_ws;
    __half* feat = (__half*)ws;            ws += (size_t)N * 128 * sizeof(__half); // 25.6MB
    float*  el   = (float*)ws;             ws += (size_t)N * 4 * sizeof(float);    // 1.6MB
    float*  er   = (float*)ws;             ws += (size_t)N * 4 * sizeof(float);    // 1.6MB
    __half* w16t = (__half*)ws;            ws += 128 * 128 * sizeof(__half);       // 32KB
    int*    off  = (int*)ws;

    hipLaunchKernelGGL(prep_seg_kernel, dim3(64 + (E + 255) / 256), dim3(256), 0, stream,
                       W, w16t, dst, off, E, N);
    hipLaunchKernelGGL(proj_kernel, dim3((N + 63) / 64), dim3(256), 0, stream,
                       h, w16t, attn_l, attn_r, feat, el, er, N);
    hipLaunchKernelGGL(aggregate_kernel, dim3((N + 3) / 4), dim3(256), 0, stream,
                       feat, el, er, off, src, bias, out, N);
}